// Round 3
// baseline (828.396 us; speedup 1.0000x reference)
//
#include <hip/hip_runtime.h>
#include <cstdint>

// Problem constants
#define NN 8192      // nodes
#define FF 512       // input features
#define FO 64        // per-head output features
#define NH 8         // heads
#define LDVT 8192    // V_t row stride (elements) -- V_t is (640 rows x 8192 k) bf16
#define LDYE 520     // Y row stride (elements): 512 numerator cols + 8 denom cols
#define YPART (8192 * 520)
#define SPLITK 6

typedef __attribute__((ext_vector_type(8))) __bf16 bf16x8;
typedef __attribute__((ext_vector_type(4))) float f32x4;

__device__ __forceinline__ unsigned short f2bf(float f) {
    // round-to-nearest-even f32 -> bf16 bits
    unsigned int u = __float_as_uint(f);
    u += 0x7fffu + ((u >> 16) & 1u);
    return (unsigned short)(u >> 16);
}

__device__ __forceinline__ void gload16(const void* g, void* l) {
    // async global->LDS, 16B per lane (emits global_load_lds_dwordx4)
    __builtin_amdgcn_global_load_lds(
        (const __attribute__((address_space(1))) unsigned int*)g,
        (__attribute__((address_space(3))) unsigned int*)l,
        16, 0, 0);
}

// ---------------------------------------------------------------------------
// K0: convert A (fp32, values in {0.0,1.0} -- exact in bf16) to bf16.
// ---------------------------------------------------------------------------
__global__ __launch_bounds__(256) void k_convA(const uint4* __restrict__ A,
                                               uint4* __restrict__ Ab) {
    size_t i = (size_t)blockIdx.x * 256 + threadIdx.x;
    uint4 a = A[2 * i];
    uint4 b = A[2 * i + 1];
    uint4 o;
    o.x = (a.x >> 16) | (a.y & 0xffff0000u);
    o.y = (a.z >> 16) | (a.w & 0xffff0000u);
    o.z = (b.x >> 16) | (b.y & 0xffff0000u);
    o.w = (b.z >> 16) | (b.w & 0xffff0000u);
    Ab[i] = o;
}

// ---------------------------------------------------------------------------
// K1: per (head, 128-node tile): WX = X @ kernels[h] in fp32 (8x4 register
// tile per thread, float4 k-unroll), s2 = WX . a2, e = exp(s2), write
// V_t[h*64+o][m] = bf16(e[m]*WX[m][o]) and V_t[512+h][m] = bf16(e[m]).
// ---------------------------------------------------------------------------
union K1Smem {
    struct { float Xs[128][36]; float Ks[32][68]; } s;                    // 26.5 KB
    struct { float red[128][16]; float es[128]; unsigned short Vs[64][136]; } r;
};

__global__ __launch_bounds__(256) void k_buildV(const float* __restrict__ X,
                                                const float* __restrict__ Kw,
                                                const float* __restrict__ Aw,
                                                unsigned short* __restrict__ Vt) {
    __shared__ K1Smem sm;
    const int t = threadIdx.x;
    const int n0 = blockIdx.x * 128;  // node tile base
    const int h = blockIdx.y;
    const int tr = t >> 4;            // 0..15: row group (owns rows tr+16i, i=0..7)
    const int tc = t & 15;            // 0..15: col group (owns cols 4*tc..4*tc+3)

    float4 acc[8];                    // acc[i] = cols 4tc..4tc+3 of row tr+16i
    for (int i = 0; i < 8; ++i) acc[i] = float4{0.f, 0.f, 0.f, 0.f};

    const int xrow = t >> 3, xcq = t & 7;          // X staging: 4 float4/thread
    const int krow0 = t >> 4, kc0 = t & 15;        // K staging: 2 float4/thread

    for (int f0 = 0, s = 0; f0 < FF; f0 += 32, ++s) {
        if (s) __syncthreads();
        // stage X tile: 128 rows x 32 f
        for (int j = 0; j < 4; ++j) {
            int row = xrow + j * 32;
            *(float4*)&sm.s.Xs[row][xcq * 4] =
                *(const float4*)(X + (size_t)(n0 + row) * FF + f0 + xcq * 4);
        }
        // stage K tile: 32 k x 64 o
        for (int j = 0; j < 2; ++j) {
            int kr = krow0 + j * 16;
            *(float4*)&sm.s.Ks[kr][kc0 * 4] =
                *(const float4*)(Kw + (size_t)h * FF * FO + (size_t)(f0 + kr) * FO + kc0 * 4);
        }
        __syncthreads();
#pragma unroll
        for (int kq = 0; kq < 8; ++kq) {
            const int k = kq * 4;
            float4 kv0 = *(const float4*)&sm.s.Ks[k + 0][tc * 4];
            float4 kv1 = *(const float4*)&sm.s.Ks[k + 1][tc * 4];
            float4 kv2 = *(const float4*)&sm.s.Ks[k + 2][tc * 4];
            float4 kv3 = *(const float4*)&sm.s.Ks[k + 3][tc * 4];
#pragma unroll
            for (int i = 0; i < 8; ++i) {
                float4 xv = *(const float4*)&sm.s.Xs[tr + 16 * i][k];
                acc[i].x += xv.x * kv0.x + xv.y * kv1.x + xv.z * kv2.x + xv.w * kv3.x;
                acc[i].y += xv.x * kv0.y + xv.y * kv1.y + xv.z * kv2.y + xv.w * kv3.y;
                acc[i].z += xv.x * kv0.z + xv.y * kv1.z + xv.z * kv2.z + xv.w * kv3.z;
                acc[i].w += xv.x * kv0.w + xv.y * kv1.w + xv.z * kv2.w + xv.w * kv3.w;
            }
        }
    }
    __syncthreads();   // done with Xs/Ks; union region reused below

    // s2 partials: per (row, tc), dot of this thread's 4 cols with a2
    float4 a2v = *(const float4*)(Aw + h * 128 + 64 + tc * 4);
    for (int i = 0; i < 8; ++i)
        sm.r.red[tr + 16 * i][tc] =
            acc[i].x * a2v.x + acc[i].y * a2v.y + acc[i].z * a2v.z + acc[i].w * a2v.w;
    __syncthreads();
    if (t < 128) {
        float s = 0.f;
        for (int c = 0; c < 16; ++c) s += sm.r.red[t][c];
        sm.r.es[t] = __expf(s);
    }
    __syncthreads();
    float ev[8];
    for (int i = 0; i < 8; ++i) ev[i] = sm.r.es[tr + 16 * i];
    // transpose V tile through LDS so global writes are k-contiguous
    for (int i = 0; i < 8; ++i) {
        int row = tr + 16 * i;
        sm.r.Vs[tc * 4 + 0][row] = f2bf(ev[i] * acc[i].x);
        sm.r.Vs[tc * 4 + 1][row] = f2bf(ev[i] * acc[i].y);
        sm.r.Vs[tc * 4 + 2][row] = f2bf(ev[i] * acc[i].z);
        sm.r.Vs[tc * 4 + 3][row] = f2bf(ev[i] * acc[i].w);
    }
    __syncthreads();
    // FIX (R2 bug): 64 o-rows x 128 nodes = 1024 uint4s, was only writing 512
    for (int j2 = 0; j2 < 4; ++j2) {
        int vid = t + j2 * 256;           // 0..1023
        int o = vid >> 4, c = vid & 15;   // o: 0..63, c: 0..15 (8 nodes each)
        *(uint4*)(Vt + (size_t)(h * 64 + o) * LDVT + n0 + c * 8) =
            *(const uint4*)&sm.r.Vs[o][c * 8];
    }
    if (t < 128) Vt[(size_t)(512 + h) * LDVT + n0 + t] = f2bf(sm.r.es[t]);
    // rows 520..639 of V_t stay poisoned (~3e-13 magnitude) -> those Y cols
    // are never stored (col<520 guard in k_gemm).
}

// ---------------------------------------------------------------------------
// K2: Y = A_bf16 (8192x8192) @ V_t^T (8192x640), bf16 MFMA, fp32 acc.
// BM=128, BN=160, BK=32; 4 waves in 2x2; wave tile 64x80 (4x5 MFMA tiles).
// Split-K = 6 (grid.z) into separate Y buffers -> 1536 blocks = 6/CU.
// ---------------------------------------------------------------------------
__global__ __launch_bounds__(256) void k_gemm(const unsigned short* __restrict__ Ab,
                                              const unsigned short* __restrict__ Vt,
                                              float* __restrict__ Y) {
    __shared__ unsigned short As[4096];   // 128 rows * 32 k, 8 KB
    __shared__ unsigned short Bs[5120];   // 160 rows * 32 k, 10 KB
    const int t = threadIdx.x;
    const int ct = blockIdx.x;    // 0..3   (col tile, 160 V-rows)
    const int rt = blockIdx.y;    // 0..63  (row tile, 128 A-rows)
    const int part = blockIdx.z;  // 0..5   (k split)
    const int ks0 = (part * 256) / SPLITK;
    const int ks1 = ((part + 1) * 256) / SPLITK;

    const int ga0 = t, ga1 = t + 256;
    const unsigned short* aS0 = Ab + ((size_t)(rt * 128 + (ga0 & 127)) << 13) + (ga0 >> 7) * 8;
    const unsigned short* aS1 = Ab + ((size_t)(rt * 128 + (ga1 & 127)) << 13) + (ga1 >> 7) * 8;
    unsigned short* aD0 = As + ga0 * 8;
    unsigned short* aD1 = As + ga1 * 8;

    const int gb0 = t, gb1 = t + 256, gb2 = t + 512;
    const int nb0 = gb0 % 160, kq0 = gb0 / 160;
    const int nb1 = gb1 % 160, kq1 = gb1 / 160;
    const int nb2 = gb2 % 160, kq2 = gb2 / 160;
    const unsigned short* bS0 = Vt + ((size_t)(ct * 160 + nb0) << 13) + kq0 * 8;
    const unsigned short* bS1 = Vt + ((size_t)(ct * 160 + nb1) << 13) + kq1 * 8;
    const unsigned short* bS2 = Vt + ((size_t)(ct * 160 + nb2) << 13) + kq2 * 8;
    unsigned short* bD0 = Bs + gb0 * 8;
    unsigned short* bD1 = Bs + gb1 * 8;
    unsigned short* bD2 = Bs + gb2 * 8;

    const int lane = t & 63;
    const int w = t >> 6;
    const int wm = w >> 1, wn = w & 1;
    const int quad = lane >> 4, l15 = lane & 15;

    const bf16x8* aF[4];
    const bf16x8* bF[5];
    for (int i = 0; i < 4; ++i)
        aF[i] = (const bf16x8*)(As + (size_t)(quad * 128 + wm * 64 + i * 16 + l15) * 8);
    for (int j = 0; j < 5; ++j)
        bF[j] = (const bf16x8*)(Bs + (size_t)(quad * 160 + wn * 80 + j * 16 + l15) * 8);

    f32x4 acc[4][5] = {};

    for (int ks = ks0; ks < ks1; ++ks) {
        const int ko = ks * 32;
        gload16(aS0 + ko, aD0);
        gload16(aS1 + ko, aD1);
        gload16(bS0 + ko, bD0);
        gload16(bS1 + ko, bD1);
        if (t < 128) gload16(bS2 + ko, bD2);
        __syncthreads();   // drains vmcnt (barrier semantics)
        bf16x8 av[4], bv[5];
        for (int i = 0; i < 4; ++i) av[i] = aF[i][0];
        for (int j = 0; j < 5; ++j) bv[j] = bF[j][0];
        for (int i = 0; i < 4; ++i)
            for (int j = 0; j < 5; ++j)
                acc[i][j] = __builtin_amdgcn_mfma_f32_16x16x32_bf16(av[i], bv[j], acc[i][j], 0, 0, 0);
        __syncthreads();   // protect LDS from next iteration's staging
    }

    // C/D layout: col = lane&15, row = (lane>>4)*4 + reg  [m89/m91 verified]
    float* Yp = Y + (size_t)part * YPART;
    for (int i = 0; i < 4; ++i) {
        int row = rt * 128 + wm * 64 + i * 16 + quad * 4;
        for (int j = 0; j < 5; ++j) {
            int col = ct * 160 + wn * 80 + j * 16 + l15;
            if (col < 520) {
                for (int r = 0; r < 4; ++r)
                    Yp[(size_t)(row + r) * LDYE + col] = acc[i][j][r];
            }
        }
    }
}

// ---------------------------------------------------------------------------
// K3: out[n, h*64+o] = relu( sum_p Ynum / sum_p Yden )
// ---------------------------------------------------------------------------
__global__ __launch_bounds__(256) void k_epi(const float* __restrict__ Y,
                                             float* __restrict__ out) {
    int idx = blockIdx.x * 256 + threadIdx.x;   // one float4 of out each
    int n = idx >> 7;
    int c = (idx & 127) * 4;
    int h = c >> 6;
    float4 u = {0.f, 0.f, 0.f, 0.f};
    float den = 0.f;
    const float* yp = Y + (size_t)n * LDYE;
#pragma unroll
    for (int p = 0; p < SPLITK; ++p) {
        float4 v = *(const float4*)(yp + c);
        u.x += v.x; u.y += v.y; u.z += v.z; u.w += v.w;
        den += yp[512 + h];
        yp += (size_t)YPART;
    }
    float inv = 1.0f / den;
    float4 o;
    o.x = fmaxf(u.x * inv, 0.f);
    o.y = fmaxf(u.y * inv, 0.f);
    o.z = fmaxf(u.z * inv, 0.f);
    o.w = fmaxf(u.w * inv, 0.f);
    *(float4*)(out + (size_t)n * 512 + c) = o;
}

extern "C" void kernel_launch(void* const* d_in, const int* in_sizes, int n_in,
                              void* d_out, int out_size, void* d_ws, size_t ws_size,
                              hipStream_t stream) {
    const float* X  = (const float*)d_in[0];   // (8192, 512)
    const float* A  = (const float*)d_in[1];   // (8192, 8192)
    const float* Kw = (const float*)d_in[2];   // (8, 512, 64)
    const float* Aw = (const float*)d_in[3];   // (8, 128)
    float* out = (float*)d_out;                // (8192, 512)
    char* ws = (char*)d_ws;
    // ws layout: A_bf16 128 MiB | V_t 10 MiB | Y parts 6 * 16.25 MiB (~236 MiB)
    unsigned short* Ab = (unsigned short*)ws;
    unsigned short* Vt = (unsigned short*)(ws + (size_t)134217728);
    float* Yb = (float*)(ws + (size_t)134217728 + (size_t)10485760);

    k_convA<<<dim3(32768), dim3(256), 0, stream>>>((const uint4*)A, (uint4*)Ab);
    k_buildV<<<dim3(64, 8), dim3(256), 0, stream>>>(X, Kw, Aw, Vt);
    k_gemm<<<dim3(4, 64, SPLITK), dim3(256), 0, stream>>>(Ab, Vt, Yb);
    k_epi<<<dim3(4096), dim3(256), 0, stream>>>(Yb, out);
}

// Round 5
// 622.011 us; speedup vs baseline: 1.3318x; 1.3318x over previous
//
#include <hip/hip_runtime.h>
#include <cstdint>

// Problem constants
#define NN 8192      // nodes
#define FF 512       // input features
#define FO 64        // per-head output features
#define NH 8         // heads
#define LDVT 8192    // V_t row stride (elements) -- V_t is (640 rows x 8192 k) bf16
#define LDYE 520     // Y row stride (elements): 512 numerator cols + 8 denom cols
#define YPART (8192 * 520)
#define SPLITK 6

typedef __attribute__((ext_vector_type(8))) __bf16 bf16x8;
typedef __attribute__((ext_vector_type(4))) float f32x4;

__device__ __forceinline__ unsigned short f2bf(float f) {
    // round-to-nearest-even f32 -> bf16 bits
    unsigned int u = __float_as_uint(f);
    u += 0x7fffu + ((u >> 16) & 1u);
    return (unsigned short)(u >> 16);
}

__device__ __forceinline__ void gload16(const void* g, void* l) {
    // async global->LDS, 16B per lane (emits global_load_lds_dwordx4)
    __builtin_amdgcn_global_load_lds(
        (const __attribute__((address_space(1))) unsigned int*)g,
        (__attribute__((address_space(3))) unsigned int*)l,
        16, 0, 0);
}

// ---------------------------------------------------------------------------
// K0: convert A (fp32, {0.0,1.0} -- exact in bf16 via truncation) to bf16.
// ---------------------------------------------------------------------------
__global__ __launch_bounds__(256) void k_convA(const uint4* __restrict__ A,
                                               uint4* __restrict__ Ab) {
    size_t i = (size_t)blockIdx.x * 256 + threadIdx.x;
    uint4 a = A[2 * i];
    uint4 b = A[2 * i + 1];
    uint4 o;
    o.x = (a.x >> 16) | (a.y & 0xffff0000u);
    o.y = (a.z >> 16) | (a.w & 0xffff0000u);
    o.z = (b.x >> 16) | (b.y & 0xffff0000u);
    o.w = (b.z >> 16) | (b.w & 0xffff0000u);
    Ab[i] = o;
}

// ---------------------------------------------------------------------------
// K0b: prep for k_wx. Blocks [0,2048): X fp32 -> bf16 (RNE), 8 elems/thread.
// Blocks [2048,2056): kernels (h,f,o) fp32 -> Kt (h,o,f) bf16 (tiny).
// ---------------------------------------------------------------------------
__global__ __launch_bounds__(256) void k_prep(const float* __restrict__ X,
                                              const float* __restrict__ Kw,
                                              unsigned short* __restrict__ Xb,
                                              unsigned short* __restrict__ Ktb) {
    const int b = blockIdx.x;
    const int t = threadIdx.x;
    if (b < 2048) {
        size_t base = ((size_t)b * 256 + t) * 8;
        float4 a = *(const float4*)(X + base);
        float4 c = *(const float4*)(X + base + 4);
        ushort4 o0, o1;
        o0.x = f2bf(a.x); o0.y = f2bf(a.y); o0.z = f2bf(a.z); o0.w = f2bf(a.w);
        o1.x = f2bf(c.x); o1.y = f2bf(c.y); o1.z = f2bf(c.z); o1.w = f2bf(c.w);
        *(ushort4*)(Xb + base) = o0;
        *(ushort4*)(Xb + base + 4) = o1;
    } else {
        int h = b - 2048;
        for (int e = t; e < FF * FO; e += 256) {
            int o = e >> 9, f = e & 511;   // write coalesced in f
            Ktb[(size_t)h * FF * FO + e] = f2bf(Kw[(size_t)h * FF * FO + (size_t)f * FO + o]);
        }
    }
}

// ---------------------------------------------------------------------------
// K1: per (head, 128-node tile): WX = Xb @ Kt^T via bf16 MFMA (K=512),
// s2 = WX . a2 (in-register shfl_xor reduce), e = exp(s2),
// V_t[h*64+o][n] = bf16(e*WX[n][o]), V_t[512+h][n] = bf16(e).
// 4 waves; wave tile 32 rows x 64 cols = 2x4 MFMA tiles (acc 32 AGPR).
// ---------------------------------------------------------------------------
union WxSmem {
    struct { unsigned short Xs[4096]; unsigned short Ks[2048]; } s;  // 12 KB granule layout
    unsigned short Vs[64][136];                                      // 17.4 KB transpose buf
};

__global__ __launch_bounds__(256) void k_wx(const unsigned short* __restrict__ Xb,
                                            const unsigned short* __restrict__ Ktb,
                                            const float* __restrict__ Aw,
                                            unsigned short* __restrict__ Vt) {
    __shared__ WxSmem sm;
    const int t = threadIdx.x;
    const int n0 = blockIdx.x * 128;
    const int h = blockIdx.y;
    const int lane = t & 63, w = t >> 6;
    const int quad = lane >> 4, l15 = lane & 15;

    // staging: Xs granule g = kq*128 + row  (row = g&127, kq = g>>7)
    const unsigned short* xS0 = Xb + (size_t)(n0 + (t & 127)) * FF + (t >> 7) * 8;
    const unsigned short* xS1 = Xb + (size_t)(n0 + ((t + 256) & 127)) * FF + ((t + 256) >> 7) * 8;
    unsigned short* xD0 = sm.s.Xs + t * 8;
    unsigned short* xD1 = sm.s.Xs + (t + 256) * 8;
    // Ks granule g = kq*64 + orow  (orow = g&63, kq = g>>6)
    const unsigned short* kS = Ktb + (size_t)h * FF * FO + (size_t)(t & 63) * FF + (t >> 6) * 8;
    unsigned short* kD = sm.s.Ks + t * 8;

    const bf16x8* aF[2];
    const bf16x8* bF[4];
    for (int i = 0; i < 2; ++i)
        aF[i] = (const bf16x8*)(sm.s.Xs + (size_t)(quad * 128 + w * 32 + i * 16 + l15) * 8);
    for (int j = 0; j < 4; ++j)
        bF[j] = (const bf16x8*)(sm.s.Ks + (size_t)(quad * 64 + j * 16 + l15) * 8);

    f32x4 acc[2][4] = {};
    for (int f0 = 0; f0 < FF; f0 += 32) {
        gload16(xS0 + f0, xD0);
        gload16(xS1 + f0, xD1);
        gload16(kS + f0, kD);
        __syncthreads();
        bf16x8 av[2], bv[4];
        for (int i = 0; i < 2; ++i) av[i] = aF[i][0];
        for (int j = 0; j < 4; ++j) bv[j] = bF[j][0];
        for (int i = 0; i < 2; ++i)
            for (int j = 0; j < 4; ++j)
                acc[i][j] = __builtin_amdgcn_mfma_f32_16x16x32_bf16(av[i], bv[j], acc[i][j], 0, 0, 0);
        __syncthreads();
    }

    // s2 per node row; C layout: col = l15 (+16j), row = quad*4 + r (+16i + 32w)
    float a2v[4];
    for (int j = 0; j < 4; ++j) a2v[j] = Aw[h * 128 + 64 + j * 16 + l15];
    float ex[2][4];
    for (int i = 0; i < 2; ++i)
        for (int r = 0; r < 4; ++r) {
            float p = acc[i][0][r] * a2v[0] + acc[i][1][r] * a2v[1]
                    + acc[i][2][r] * a2v[2] + acc[i][3][r] * a2v[3];
            p += __shfl_xor(p, 1);
            p += __shfl_xor(p, 2);
            p += __shfl_xor(p, 4);
            p += __shfl_xor(p, 8);
            ex[i][r] = __expf(p);
        }

    // scale + transpose through LDS (loop-end barrier protects Xs/Ks reuse)
    for (int i = 0; i < 2; ++i)
        for (int j = 0; j < 4; ++j)
            for (int r = 0; r < 4; ++r) {
                int row = w * 32 + i * 16 + quad * 4 + r;
                int col = j * 16 + l15;
                sm.Vs[col][row] = f2bf(ex[i][r] * acc[i][j][r]);
            }
    __syncthreads();
    // FIX (R4 bug): 64 o-rows x 128 nodes = 8192 shorts = 1024 uint4,
    // was writing only 512 (o-rows 0..31) -> half of V stayed poisoned.
    for (int j2 = 0; j2 < 4; ++j2) {
        int vid = t + j2 * 256;           // 0..1023
        int o = vid >> 4, c = vid & 15;   // o: 0..63, c: 0..15 (8 nodes each)
        *(uint4*)(Vt + (size_t)(h * 64 + o) * LDVT + n0 + c * 8) =
            *(const uint4*)&sm.Vs[o][c * 8];
    }
    if (l15 == 0) {
        for (int i = 0; i < 2; ++i)
            for (int r = 0; r < 4; ++r) {
                int row = w * 32 + i * 16 + quad * 4 + r;
                Vt[(size_t)(512 + h) * LDVT + n0 + row] = f2bf(ex[i][r]);
            }
    }
    // rows 520..639 of V_t stay poisoned -> those Y cols never stored (guard).
}

// ---------------------------------------------------------------------------
// K2: Y = A_bf16 (8192x8192) @ V_t^T (8192x640), bf16 MFMA, fp32 acc.
// BM=128, BN=160, BK=32; 4 waves 2x2; wave tile 64x80 (4x5 tiles, 80 AGPR).
// 1D grid 1536 with XCD swizzle: the 4 ct-blocks sharing an A stripe get
// ids {u*8+xcd : u consecutive} -> same XCD (id%8 round-robin) + adjacent
// dispatch -> A re-reads hit XCD-local L2 instead of re-fetching 4x.
// ---------------------------------------------------------------------------
__global__ __launch_bounds__(256) void k_gemm(const unsigned short* __restrict__ Ab,
                                              const unsigned short* __restrict__ Vt,
                                              float* __restrict__ Y) {
    __shared__ unsigned short As[4096];   // 128 rows * 32 k, 8 KB
    __shared__ unsigned short Bs[5120];   // 160 rows * 32 k, 10 KB
    const int t = threadIdx.x;
    // swizzled decode
    const int id = blockIdx.x;
    const int xcd = id & 7;
    const int u = id >> 3;                 // 0..191
    const int ct = u & 3;                  // 0..3
    const int rp = ((u >> 2) << 3) | xcd;  // 0..383
    const int rt = rp & 63;                // 0..63
    const int part = rp >> 6;              // 0..5
    const int ks0 = (part * 256) / SPLITK;
    const int ks1 = ((part + 1) * 256) / SPLITK;

    const int ga0 = t, ga1 = t + 256;
    const unsigned short* aS0 = Ab + ((size_t)(rt * 128 + (ga0 & 127)) << 13) + (ga0 >> 7) * 8;
    const unsigned short* aS1 = Ab + ((size_t)(rt * 128 + (ga1 & 127)) << 13) + (ga1 >> 7) * 8;
    unsigned short* aD0 = As + ga0 * 8;
    unsigned short* aD1 = As + ga1 * 8;

    const int gb0 = t, gb1 = t + 256, gb2 = t + 512;
    const int nb0 = gb0 % 160, kq0 = gb0 / 160;
    const int nb1 = gb1 % 160, kq1 = gb1 / 160;
    const int nb2 = gb2 % 160, kq2 = gb2 / 160;
    const unsigned short* bS0 = Vt + ((size_t)(ct * 160 + nb0) << 13) + kq0 * 8;
    const unsigned short* bS1 = Vt + ((size_t)(ct * 160 + nb1) << 13) + kq1 * 8;
    const unsigned short* bS2 = Vt + ((size_t)(ct * 160 + nb2) << 13) + kq2 * 8;
    unsigned short* bD0 = Bs + gb0 * 8;
    unsigned short* bD1 = Bs + gb1 * 8;
    unsigned short* bD2 = Bs + gb2 * 8;

    const int lane = t & 63;
    const int w = t >> 6;
    const int wm = w >> 1, wn = w & 1;
    const int quad = lane >> 4, l15 = lane & 15;

    const bf16x8* aF[4];
    const bf16x8* bF[5];
    for (int i = 0; i < 4; ++i)
        aF[i] = (const bf16x8*)(As + (size_t)(quad * 128 + wm * 64 + i * 16 + l15) * 8);
    for (int j = 0; j < 5; ++j)
        bF[j] = (const bf16x8*)(Bs + (size_t)(quad * 160 + wn * 80 + j * 16 + l15) * 8);

    f32x4 acc[4][5] = {};

    for (int ks = ks0; ks < ks1; ++ks) {
        const int ko = ks * 32;
        gload16(aS0 + ko, aD0);
        gload16(aS1 + ko, aD1);
        gload16(bS0 + ko, bD0);
        gload16(bS1 + ko, bD1);
        if (t < 128) gload16(bS2 + ko, bD2);
        __syncthreads();   // drains vmcnt (barrier semantics)
        bf16x8 av[4], bv[5];
        for (int i = 0; i < 4; ++i) av[i] = aF[i][0];
        for (int j = 0; j < 5; ++j) bv[j] = bF[j][0];
        for (int i = 0; i < 4; ++i)
            for (int j = 0; j < 5; ++j)
                acc[i][j] = __builtin_amdgcn_mfma_f32_16x16x32_bf16(av[i], bv[j], acc[i][j], 0, 0, 0);
        __syncthreads();   // protect LDS from next iteration's staging
    }

    // C/D layout: col = lane&15, row = (lane>>4)*4 + reg
    float* Yp = Y + (size_t)part * YPART;
    for (int i = 0; i < 4; ++i) {
        int row = rt * 128 + wm * 64 + i * 16 + quad * 4;
        for (int j = 0; j < 5; ++j) {
            int col = ct * 160 + wn * 80 + j * 16 + l15;
            if (col < 520) {
                for (int r = 0; r < 4; ++r)
                    Yp[(size_t)(row + r) * LDYE + col] = acc[i][j][r];
            }
        }
    }
}

// ---------------------------------------------------------------------------
// K3: out[n, h*64+o] = relu( sum_p Ynum / sum_p Yden )
// ---------------------------------------------------------------------------
__global__ __launch_bounds__(256) void k_epi(const float* __restrict__ Y,
                                             float* __restrict__ out) {
    int idx = blockIdx.x * 256 + threadIdx.x;   // one float4 of out each
    int n = idx >> 7;
    int c = (idx & 127) * 4;
    int h = c >> 6;
    float4 u = {0.f, 0.f, 0.f, 0.f};
    float den = 0.f;
    const float* yp = Y + (size_t)n * LDYE;
#pragma unroll
    for (int p = 0; p < SPLITK; ++p) {
        float4 v = *(const float4*)(yp + c);
        u.x += v.x; u.y += v.y; u.z += v.z; u.w += v.w;
        den += yp[512 + h];
        yp += (size_t)YPART;
    }
    float inv = 1.0f / den;
    float4 o;
    o.x = fmaxf(u.x * inv, 0.f);
    o.y = fmaxf(u.y * inv, 0.f);
    o.z = fmaxf(u.z * inv, 0.f);
    o.w = fmaxf(u.w * inv, 0.f);
    *(float4*)(out + (size_t)n * 512 + c) = o;
}

extern "C" void kernel_launch(void* const* d_in, const int* in_sizes, int n_in,
                              void* d_out, int out_size, void* d_ws, size_t ws_size,
                              hipStream_t stream) {
    const float* X  = (const float*)d_in[0];   // (8192, 512)
    const float* A  = (const float*)d_in[1];   // (8192, 8192)
    const float* Kw = (const float*)d_in[2];   // (8, 512, 64)
    const float* Aw = (const float*)d_in[3];   // (8, 128)
    float* out = (float*)d_out;                // (8192, 512)
    char* ws = (char*)d_ws;
    // ws layout: Ab 128 MiB | Vt 10 MiB | Yb 97.5 MiB (total 235.5 MiB).
    // Xb (8 MiB) + Ktb (0.5 MiB) ALIAS the head of Yb: consumed by k_wx
    // before k_gemm overwrites every Yb byte (all cols<520 stored, all parts).
    unsigned short* Ab = (unsigned short*)ws;
    unsigned short* Vt = (unsigned short*)(ws + (size_t)134217728);
    float* Yb = (float*)(ws + (size_t)134217728 + (size_t)10485760);
    unsigned short* Xb = (unsigned short*)Yb;
    unsigned short* Ktb = Xb + (size_t)NN * FF;

    k_convA<<<dim3(32768), dim3(256), 0, stream>>>((const uint4*)A, (uint4*)Ab);
    k_prep<<<dim3(2056), dim3(256), 0, stream>>>(X, Kw, Xb, Ktb);
    k_wx<<<dim3(64, 8), dim3(256), 0, stream>>>(Xb, Ktb, Aw, Vt);
    k_gemm<<<dim3(1536), dim3(256), 0, stream>>>(Ab, Vt, Yb);
    k_epi<<<dim3(4096), dim3(256), 0, stream>>>(Yb, out);
}